// Round 1
// baseline (3281.179 us; speedup 1.0000x reference)
//
#include <hip/hip_runtime.h>

#define C 128
#define TILE 64          // rows (edges/nodes) per block
#define THREADS 256      // 4 waves; each half-wave owns 8 rows; each lane 4 out-cols

// ---------- shared micro-GEMM: [8 rows x 4 cols] per thread, K=128 ----------
__device__ __forceinline__ void zero_acc(float acc[8][4]) {
#pragma unroll
    for (int j = 0; j < 8; ++j)
#pragma unroll
        for (int i = 0; i < 4; ++i) acc[j][i] = 0.f;
}

// acc[j][i] += sum_kc s_in[rg*8+j][kc] * W[kc][oc0+i]
__device__ __forceinline__ void tile_gemm(const float* __restrict__ s_in,
                                          const float* __restrict__ W,
                                          float acc[8][4], int rg, int oc0)
{
#pragma unroll 2
    for (int kc = 0; kc < C; kc += 4) {
        const float4 w0 = *(const float4*)(W + (kc + 0) * C + oc0);
        const float4 w1 = *(const float4*)(W + (kc + 1) * C + oc0);
        const float4 w2 = *(const float4*)(W + (kc + 2) * C + oc0);
        const float4 w3 = *(const float4*)(W + (kc + 3) * C + oc0);
#pragma unroll
        for (int j = 0; j < 8; ++j) {
            const float4 a = *(const float4*)(s_in + (rg * 8 + j) * C + kc); // broadcast across half-wave
            acc[j][0] = fmaf(a.w, w3.x, fmaf(a.z, w2.x, fmaf(a.y, w1.x, fmaf(a.x, w0.x, acc[j][0]))));
            acc[j][1] = fmaf(a.w, w3.y, fmaf(a.z, w2.y, fmaf(a.y, w1.y, fmaf(a.x, w0.y, acc[j][1]))));
            acc[j][2] = fmaf(a.w, w3.z, fmaf(a.z, w2.z, fmaf(a.y, w1.z, fmaf(a.x, w0.z, acc[j][2]))));
            acc[j][3] = fmaf(a.w, w3.w, fmaf(a.z, w2.w, fmaf(a.y, w1.w, fmaf(a.x, w0.w, acc[j][3]))));
        }
    }
}

__device__ __forceinline__ void bias_relu(float acc[8][4], const float* __restrict__ b, int oc0) {
    const float4 bv = *(const float4*)(b + oc0);
#pragma unroll
    for (int j = 0; j < 8; ++j) {
        acc[j][0] = fmaxf(acc[j][0] + bv.x, 0.f);
        acc[j][1] = fmaxf(acc[j][1] + bv.y, 0.f);
        acc[j][2] = fmaxf(acc[j][2] + bv.z, 0.f);
        acc[j][3] = fmaxf(acc[j][3] + bv.w, 0.f);
    }
}

__device__ __forceinline__ void store_tile(float* __restrict__ s, const float acc[8][4], int rg, int oc0) {
#pragma unroll
    for (int j = 0; j < 8; ++j) {
        float4 t; t.x = acc[j][0]; t.y = acc[j][1]; t.z = acc[j][2]; t.w = acc[j][3];
        *(float4*)(s + (rg * 8 + j) * C + oc0) = t;
    }
}

__device__ __forceinline__ void atomic_add_f32(float* p, float v) {
    __hip_atomic_fetch_add(p, v, __ATOMIC_RELAXED, __HIP_MEMORY_SCOPE_AGENT);
}

// ---------- kernel 1: h = relu(x@W_in+b_in); q=h@W_dst; k=h@W_src; v=h@W_lin ----------
extern "C" __global__ void __launch_bounds__(THREADS, 2)
node_qkv(const float* __restrict__ x,
         const float* __restrict__ W_in, const float* __restrict__ b_in,
         const float* __restrict__ W_lin, const float* __restrict__ W_src, const float* __restrict__ W_dst,
         float* __restrict__ q, float* __restrict__ k, float* __restrict__ v, int N)
{
    __shared__ __align__(16) float s_in[TILE * C];
    const int tx = threadIdx.x;
    const int rg = tx >> 5;
    const int oc0 = (tx & 31) << 2;
    const int row0 = blockIdx.x * TILE;

#pragma unroll
    for (int j = 0; j < 8; ++j) {
        const int r = rg * 8 + j, n = row0 + r;
        float4 xv; xv.x = xv.y = xv.z = xv.w = 0.f;
        if (n < N) xv = *(const float4*)(x + n * C + oc0);
        *(float4*)(s_in + r * C + oc0) = xv;
    }
    // no __syncthreads needed anywhere: each half-wave only touches its own 8 rows

    float acc[8][4];
    zero_acc(acc);
    tile_gemm(s_in, W_in, acc, rg, oc0);
    bias_relu(acc, b_in, oc0);
    store_tile(s_in, acc, rg, oc0);          // s_in now holds h

    // q = h @ W_dst
    zero_acc(acc);
    tile_gemm(s_in, W_dst, acc, rg, oc0);
#pragma unroll
    for (int j = 0; j < 8; ++j) {
        const int n = row0 + rg * 8 + j;
        if (n < N) { float4 t; t.x=acc[j][0]; t.y=acc[j][1]; t.z=acc[j][2]; t.w=acc[j][3];
                     *(float4*)(q + n * C + oc0) = t; }
    }
    // k = h @ W_src
    zero_acc(acc);
    tile_gemm(s_in, W_src, acc, rg, oc0);
#pragma unroll
    for (int j = 0; j < 8; ++j) {
        const int n = row0 + rg * 8 + j;
        if (n < N) { float4 t; t.x=acc[j][0]; t.y=acc[j][1]; t.z=acc[j][2]; t.w=acc[j][3];
                     *(float4*)(k + n * C + oc0) = t; }
    }
    // v = h @ W_lin
    zero_acc(acc);
    tile_gemm(s_in, W_lin, acc, rg, oc0);
#pragma unroll
    for (int j = 0; j < 8; ++j) {
        const int n = row0 + rg * 8 + j;
        if (n < N) { float4 t; t.x=acc[j][0]; t.y=acc[j][1]; t.z=acc[j][2]; t.w=acc[j][3];
                     *(float4*)(v + n * C + oc0) = t; }
    }
}

// ---------- kernel 2: per-edge MLPs + softmax-numerator accumulation ----------
// z[dst,c]    += exp(alpha)
// aggU[dst,c] += exp(alpha) * (v[src,c] + delta[c])
extern "C" __global__ void __launch_bounds__(THREADS, 2)
edge_kernel(const float* __restrict__ pos, const int* __restrict__ ei,
            const float* __restrict__ q, const float* __restrict__ k, const float* __restrict__ v,
            const float* __restrict__ pw1, const float* __restrict__ pb1,
            const float* __restrict__ pw2, const float* __restrict__ pb2,
            const float* __restrict__ aw1, const float* __restrict__ ab1,
            const float* __restrict__ aw2, const float* __restrict__ ab2,
            float* __restrict__ z, float* __restrict__ aggU, int E)
{
    __shared__ __align__(16) float s_in[TILE * C];
    const int tx = threadIdx.x;
    const int rg = tx >> 5;
    const int oc0 = (tx & 31) << 2;
    const int e0 = blockIdx.x * TILE;

    int ss[8], sd[8];
#pragma unroll
    for (int j = 0; j < 8; ++j) {
        const int e = e0 + rg * 8 + j;
        const bool valid = (e < E);
        ss[j] = valid ? ei[e] : 0;
        sd[j] = valid ? ei[E + e] : 0;
    }

    // s_in = pos[dst] - pos[src]   (each half-wave gathers one full 512B row per j)
#pragma unroll
    for (int j = 0; j < 8; ++j) {
        const float4 pd = *(const float4*)(pos + sd[j] * C + oc0);
        const float4 ps = *(const float4*)(pos + ss[j] * C + oc0);
        float4 d; d.x = pd.x - ps.x; d.y = pd.y - ps.y; d.z = pd.z - ps.z; d.w = pd.w - ps.w;
        *(float4*)(s_in + (rg * 8 + j) * C + oc0) = d;
    }

    float acc[8][4];
    // pos_nn layer 1
    zero_acc(acc);
    tile_gemm(s_in, pw1, acc, rg, oc0);
    bias_relu(acc, pb1, oc0);
    store_tile(s_in, acc, rg, oc0);
    // pos_nn layer 2 -> delta (kept in registers)
    zero_acc(acc);
    tile_gemm(s_in, pw2, acc, rg, oc0);
    bias_relu(acc, pb2, oc0);
    float dl[8][4];
#pragma unroll
    for (int j = 0; j < 8; ++j)
#pragma unroll
        for (int i = 0; i < 4; ++i) dl[j][i] = acc[j][i];

    // s_in = q[dst] - k[src] + delta
#pragma unroll
    for (int j = 0; j < 8; ++j) {
        const float4 qd = *(const float4*)(q + sd[j] * C + oc0);
        const float4 kk = *(const float4*)(k + ss[j] * C + oc0);
        float4 a;
        a.x = qd.x - kk.x + dl[j][0];
        a.y = qd.y - kk.y + dl[j][1];
        a.z = qd.z - kk.z + dl[j][2];
        a.w = qd.w - kk.w + dl[j][3];
        *(float4*)(s_in + (rg * 8 + j) * C + oc0) = a;
    }

    // attn_nn layer 1
    zero_acc(acc);
    tile_gemm(s_in, aw1, acc, rg, oc0);
    bias_relu(acc, ab1, oc0);
    store_tile(s_in, acc, rg, oc0);
    // attn_nn layer 2 -> alpha
    zero_acc(acc);
    tile_gemm(s_in, aw2, acc, rg, oc0);
    bias_relu(acc, ab2, oc0);

    // alpha >= 0 and O(1): exp() safe without segment-max shift (shift-invariant softmax)
#pragma unroll
    for (int j = 0; j < 8; ++j) {
        if (e0 + rg * 8 + j < E) {
            const float4 vv = *(const float4*)(v + ss[j] * C + oc0);
            const float ea0 = __expf(acc[j][0]);
            const float ea1 = __expf(acc[j][1]);
            const float ea2 = __expf(acc[j][2]);
            const float ea3 = __expf(acc[j][3]);
            float* zp = z    + sd[j] * C + oc0;
            float* gp = aggU + sd[j] * C + oc0;
            atomic_add_f32(zp + 0, ea0);
            atomic_add_f32(zp + 1, ea1);
            atomic_add_f32(zp + 2, ea2);
            atomic_add_f32(zp + 3, ea3);
            atomic_add_f32(gp + 0, ea0 * (vv.x + dl[j][0]));
            atomic_add_f32(gp + 1, ea1 * (vv.y + dl[j][1]));
            atomic_add_f32(gp + 2, ea2 * (vv.z + dl[j][2]));
            atomic_add_f32(gp + 3, ea3 * (vv.w + dl[j][3]));
        }
    }
}

// ---------- kernel 3: out = relu( (aggU / (z+1e-16)) @ W_out + b_out ) ----------
extern "C" __global__ void __launch_bounds__(THREADS, 2)
out_kernel(const float* __restrict__ aggU, const float* __restrict__ z,
           const float* __restrict__ W_out, const float* __restrict__ b_out,
           float* __restrict__ out, int N)
{
    __shared__ __align__(16) float s_in[TILE * C];
    const int tx = threadIdx.x;
    const int rg = tx >> 5;
    const int oc0 = (tx & 31) << 2;
    const int row0 = blockIdx.x * TILE;

#pragma unroll
    for (int j = 0; j < 8; ++j) {
        const int r = rg * 8 + j, n = row0 + r;
        float4 a; a.x = a.y = a.z = a.w = 0.f;
        if (n < N) {
            const float4 g  = *(const float4*)(aggU + n * C + oc0);
            const float4 zz = *(const float4*)(z    + n * C + oc0);
            a.x = g.x / (zz.x + 1e-16f);
            a.y = g.y / (zz.y + 1e-16f);
            a.z = g.z / (zz.z + 1e-16f);
            a.w = g.w / (zz.w + 1e-16f);
        }
        *(float4*)(s_in + r * C + oc0) = a;
    }

    float acc[8][4];
    zero_acc(acc);
    tile_gemm(s_in, W_out, acc, rg, oc0);
    bias_relu(acc, b_out, oc0);
#pragma unroll
    for (int j = 0; j < 8; ++j) {
        const int n = row0 + rg * 8 + j;
        if (n < N) { float4 t; t.x=acc[j][0]; t.y=acc[j][1]; t.z=acc[j][2]; t.w=acc[j][3];
                     *(float4*)(out + n * C + oc0) = t; }
    }
}

// ---------- launch ----------
extern "C" void kernel_launch(void* const* d_in, const int* in_sizes, int n_in,
                              void* d_out, int out_size, void* d_ws, size_t ws_size,
                              hipStream_t stream)
{
    const float* x     = (const float*)d_in[0];
    const float* pos   = (const float*)d_in[1];
    const int*   ei    = (const int*)  d_in[2];
    const float* W_in  = (const float*)d_in[3];
    const float* b_in  = (const float*)d_in[4];
    const float* W_lin = (const float*)d_in[5];
    const float* W_src = (const float*)d_in[6];
    const float* W_dst = (const float*)d_in[7];
    const float* pw1   = (const float*)d_in[8];
    const float* pb1   = (const float*)d_in[9];
    const float* pw2   = (const float*)d_in[10];
    const float* pb2   = (const float*)d_in[11];
    const float* aw1   = (const float*)d_in[12];
    const float* ab1   = (const float*)d_in[13];
    const float* aw2   = (const float*)d_in[14];
    const float* ab2   = (const float*)d_in[15];
    const float* W_out = (const float*)d_in[16];
    const float* b_out = (const float*)d_in[17];

    const int N = in_sizes[0] / C;
    const int E = in_sizes[2] / 2;

    float* z    = (float*)d_ws;                  // [N,C]
    float* aggU = z    + (size_t)N * C;          // [N,C]
    float* q    = aggU + (size_t)N * C;          // [N,C]
    float* k    = q    + (size_t)N * C;          // [N,C]
    float* v    = k    + (size_t)N * C;          // [N,C]

    // zero the accumulators (ws is poisoned 0xAA before every call)
    hipMemsetAsync(z, 0, (size_t)2 * N * C * sizeof(float), stream);

    const int nb = (N + TILE - 1) / TILE;
    const int eb = (E + TILE - 1) / TILE;

    node_qkv<<<nb, THREADS, 0, stream>>>(x, W_in, b_in, W_lin, W_src, W_dst, q, k, v, N);
    edge_kernel<<<eb, THREADS, 0, stream>>>(pos, ei, q, k, v,
                                            pw1, pb1, pw2, pb2,
                                            aw1, ab1, aw2, ab2, z, aggU, E);
    out_kernel<<<nb, THREADS, 0, stream>>>(aggU, z, W_out, b_out, (float*)d_out, N);
}

// Round 2
// 3270.073 us; speedup vs baseline: 1.0034x; 1.0034x over previous
//
#include <hip/hip_runtime.h>

#define C 128
#define TILE 64          // rows (edges/nodes) per block
#define THREADS 256      // 4 waves; each half-wave owns 8 rows; each lane 4 out-cols

// ---------- shared micro-GEMM: [8 rows x 4 cols] per thread, K=128 ----------
__device__ __forceinline__ void zero_acc(float acc[8][4]) {
#pragma unroll
    for (int j = 0; j < 8; ++j)
#pragma unroll
        for (int i = 0; i < 4; ++i) acc[j][i] = 0.f;
}

// acc[j][i] += sum_kc s_in[rg*8+j][kc] * W[kc][oc0+i]
__device__ __forceinline__ void tile_gemm(const float* __restrict__ s_in,
                                          const float* __restrict__ W,
                                          float acc[8][4], int rg, int oc0)
{
#pragma unroll 2
    for (int kc = 0; kc < C; kc += 4) {
        const float4 w0 = *(const float4*)(W + (kc + 0) * C + oc0);
        const float4 w1 = *(const float4*)(W + (kc + 1) * C + oc0);
        const float4 w2 = *(const float4*)(W + (kc + 2) * C + oc0);
        const float4 w3 = *(const float4*)(W + (kc + 3) * C + oc0);
#pragma unroll
        for (int j = 0; j < 8; ++j) {
            const float4 a = *(const float4*)(s_in + (rg * 8 + j) * C + kc); // broadcast across half-wave
            acc[j][0] = fmaf(a.w, w3.x, fmaf(a.z, w2.x, fmaf(a.y, w1.x, fmaf(a.x, w0.x, acc[j][0]))));
            acc[j][1] = fmaf(a.w, w3.y, fmaf(a.z, w2.y, fmaf(a.y, w1.y, fmaf(a.x, w0.y, acc[j][1]))));
            acc[j][2] = fmaf(a.w, w3.z, fmaf(a.z, w2.z, fmaf(a.y, w1.z, fmaf(a.x, w0.z, acc[j][2]))));
            acc[j][3] = fmaf(a.w, w3.w, fmaf(a.z, w2.w, fmaf(a.y, w1.w, fmaf(a.x, w0.w, acc[j][3]))));
        }
    }
}

__device__ __forceinline__ void bias_relu(float acc[8][4], const float* __restrict__ b, int oc0) {
    const float4 bv = *(const float4*)(b + oc0);
#pragma unroll
    for (int j = 0; j < 8; ++j) {
        acc[j][0] = fmaxf(acc[j][0] + bv.x, 0.f);
        acc[j][1] = fmaxf(acc[j][1] + bv.y, 0.f);
        acc[j][2] = fmaxf(acc[j][2] + bv.z, 0.f);
        acc[j][3] = fmaxf(acc[j][3] + bv.w, 0.f);
    }
}

__device__ __forceinline__ void store_tile(float* __restrict__ s, const float acc[8][4], int rg, int oc0) {
#pragma unroll
    for (int j = 0; j < 8; ++j) {
        float4 t; t.x = acc[j][0]; t.y = acc[j][1]; t.z = acc[j][2]; t.w = acc[j][3];
        *(float4*)(s + (rg * 8 + j) * C + oc0) = t;
    }
}

__device__ __forceinline__ void atomic_add_f32(float* p, float v) {
    __hip_atomic_fetch_add(p, v, __ATOMIC_RELAXED, __HIP_MEMORY_SCOPE_AGENT);
}

// ---------- kernel 1: h = relu(x@W_in+b_in); q=h@W_dst; k=h@W_src; v=h@W_lin ----------
// __launch_bounds__: single arg only — round 1 showed the (256,2) min-waves hint
// pinned runtime occupancy at exactly 2 blocks/CU (23%); resources allow ~5.
extern "C" __global__ void __launch_bounds__(THREADS)
node_qkv(const float* __restrict__ x,
         const float* __restrict__ W_in, const float* __restrict__ b_in,
         const float* __restrict__ W_lin, const float* __restrict__ W_src, const float* __restrict__ W_dst,
         float* __restrict__ q, float* __restrict__ k, float* __restrict__ v, int N)
{
    __shared__ __align__(16) float s_in[TILE * C];
    const int tx = threadIdx.x;
    const int rg = tx >> 5;
    const int oc0 = (tx & 31) << 2;
    const int row0 = blockIdx.x * TILE;

#pragma unroll
    for (int j = 0; j < 8; ++j) {
        const int r = rg * 8 + j, n = row0 + r;
        float4 xv; xv.x = xv.y = xv.z = xv.w = 0.f;
        if (n < N) xv = *(const float4*)(x + n * C + oc0);
        *(float4*)(s_in + r * C + oc0) = xv;
    }
    // no __syncthreads needed anywhere: each half-wave only touches its own 8 rows

    float acc[8][4];
    zero_acc(acc);
    tile_gemm(s_in, W_in, acc, rg, oc0);
    bias_relu(acc, b_in, oc0);
    store_tile(s_in, acc, rg, oc0);          // s_in now holds h

    // q = h @ W_dst
    zero_acc(acc);
    tile_gemm(s_in, W_dst, acc, rg, oc0);
#pragma unroll
    for (int j = 0; j < 8; ++j) {
        const int n = row0 + rg * 8 + j;
        if (n < N) { float4 t; t.x=acc[j][0]; t.y=acc[j][1]; t.z=acc[j][2]; t.w=acc[j][3];
                     *(float4*)(q + n * C + oc0) = t; }
    }
    // k = h @ W_src
    zero_acc(acc);
    tile_gemm(s_in, W_src, acc, rg, oc0);
#pragma unroll
    for (int j = 0; j < 8; ++j) {
        const int n = row0 + rg * 8 + j;
        if (n < N) { float4 t; t.x=acc[j][0]; t.y=acc[j][1]; t.z=acc[j][2]; t.w=acc[j][3];
                     *(float4*)(k + n * C + oc0) = t; }
    }
    // v = h @ W_lin
    zero_acc(acc);
    tile_gemm(s_in, W_lin, acc, rg, oc0);
#pragma unroll
    for (int j = 0; j < 8; ++j) {
        const int n = row0 + rg * 8 + j;
        if (n < N) { float4 t; t.x=acc[j][0]; t.y=acc[j][1]; t.z=acc[j][2]; t.w=acc[j][3];
                     *(float4*)(v + n * C + oc0) = t; }
    }
}

// ---------- kernel 2: per-edge MLPs + softmax-numerator accumulation ----------
// z[dst,c]    += exp(alpha)
// aggU[dst,c] += exp(alpha) * (v[src,c] + delta[c])
extern "C" __global__ void __launch_bounds__(THREADS)
edge_kernel(const float* __restrict__ pos, const int* __restrict__ ei,
            const float* __restrict__ q, const float* __restrict__ k, const float* __restrict__ v,
            const float* __restrict__ pw1, const float* __restrict__ pb1,
            const float* __restrict__ pw2, const float* __restrict__ pb2,
            const float* __restrict__ aw1, const float* __restrict__ ab1,
            const float* __restrict__ aw2, const float* __restrict__ ab2,
            float* __restrict__ z, float* __restrict__ aggU, int E)
{
    __shared__ __align__(16) float s_in[TILE * C];
    const int tx = threadIdx.x;
    const int rg = tx >> 5;
    const int oc0 = (tx & 31) << 2;
    const int e0 = blockIdx.x * TILE;

    int ss[8], sd[8];
#pragma unroll
    for (int j = 0; j < 8; ++j) {
        const int e = e0 + rg * 8 + j;
        const bool valid = (e < E);
        ss[j] = valid ? ei[e] : 0;
        sd[j] = valid ? ei[E + e] : 0;
    }

    // s_in = pos[dst] - pos[src]   (each half-wave gathers one full 512B row per j)
#pragma unroll
    for (int j = 0; j < 8; ++j) {
        const float4 pd = *(const float4*)(pos + sd[j] * C + oc0);
        const float4 ps = *(const float4*)(pos + ss[j] * C + oc0);
        float4 d; d.x = pd.x - ps.x; d.y = pd.y - ps.y; d.z = pd.z - ps.z; d.w = pd.w - ps.w;
        *(float4*)(s_in + (rg * 8 + j) * C + oc0) = d;
    }

    float acc[8][4];
    // pos_nn layer 1
    zero_acc(acc);
    tile_gemm(s_in, pw1, acc, rg, oc0);
    bias_relu(acc, pb1, oc0);
    store_tile(s_in, acc, rg, oc0);
    // pos_nn layer 2 -> delta (kept in registers)
    zero_acc(acc);
    tile_gemm(s_in, pw2, acc, rg, oc0);
    bias_relu(acc, pb2, oc0);
    float dl[8][4];
#pragma unroll
    for (int j = 0; j < 8; ++j)
#pragma unroll
        for (int i = 0; i < 4; ++i) dl[j][i] = acc[j][i];

    // s_in = q[dst] - k[src] + delta
#pragma unroll
    for (int j = 0; j < 8; ++j) {
        const float4 qd = *(const float4*)(q + sd[j] * C + oc0);
        const float4 kk = *(const float4*)(k + ss[j] * C + oc0);
        float4 a;
        a.x = qd.x - kk.x + dl[j][0];
        a.y = qd.y - kk.y + dl[j][1];
        a.z = qd.z - kk.z + dl[j][2];
        a.w = qd.w - kk.w + dl[j][3];
        *(float4*)(s_in + (rg * 8 + j) * C + oc0) = a;
    }

    // attn_nn layer 1
    zero_acc(acc);
    tile_gemm(s_in, aw1, acc, rg, oc0);
    bias_relu(acc, ab1, oc0);
    store_tile(s_in, acc, rg, oc0);
    // attn_nn layer 2 -> alpha
    zero_acc(acc);
    tile_gemm(s_in, aw2, acc, rg, oc0);
    bias_relu(acc, ab2, oc0);

    // alpha >= 0 and O(1): exp() safe without segment-max shift (shift-invariant softmax)
#pragma unroll
    for (int j = 0; j < 8; ++j) {
        if (e0 + rg * 8 + j < E) {
            const float4 vv = *(const float4*)(v + ss[j] * C + oc0);
            const float ea0 = __expf(acc[j][0]);
            const float ea1 = __expf(acc[j][1]);
            const float ea2 = __expf(acc[j][2]);
            const float ea3 = __expf(acc[j][3]);
            float* zp = z    + sd[j] * C + oc0;
            float* gp = aggU + sd[j] * C + oc0;
            atomic_add_f32(zp + 0, ea0);
            atomic_add_f32(zp + 1, ea1);
            atomic_add_f32(zp + 2, ea2);
            atomic_add_f32(zp + 3, ea3);
            atomic_add_f32(gp + 0, ea0 * (vv.x + dl[j][0]));
            atomic_add_f32(gp + 1, ea1 * (vv.y + dl[j][1]));
            atomic_add_f32(gp + 2, ea2 * (vv.z + dl[j][2]));
            atomic_add_f32(gp + 3, ea3 * (vv.w + dl[j][3]));
        }
    }
}

// ---------- kernel 3: out = relu( (aggU / (z+1e-16)) @ W_out + b_out ) ----------
extern "C" __global__ void __launch_bounds__(THREADS)
out_kernel(const float* __restrict__ aggU, const float* __restrict__ z,
           const float* __restrict__ W_out, const float* __restrict__ b_out,
           float* __restrict__ out, int N)
{
    __shared__ __align__(16) float s_in[TILE * C];
    const int tx = threadIdx.x;
    const int rg = tx >> 5;
    const int oc0 = (tx & 31) << 2;
    const int row0 = blockIdx.x * TILE;

#pragma unroll
    for (int j = 0; j < 8; ++j) {
        const int r = rg * 8 + j, n = row0 + r;
        float4 a; a.x = a.y = a.z = a.w = 0.f;
        if (n < N) {
            const float4 g  = *(const float4*)(aggU + n * C + oc0);
            const float4 zz = *(const float4*)(z    + n * C + oc0);
            a.x = g.x / (zz.x + 1e-16f);
            a.y = g.y / (zz.y + 1e-16f);
            a.z = g.z / (zz.z + 1e-16f);
            a.w = g.w / (zz.w + 1e-16f);
        }
        *(float4*)(s_in + r * C + oc0) = a;
    }

    float acc[8][4];
    zero_acc(acc);
    tile_gemm(s_in, W_out, acc, rg, oc0);
    bias_relu(acc, b_out, oc0);
#pragma unroll
    for (int j = 0; j < 8; ++j) {
        const int n = row0 + rg * 8 + j;
        if (n < N) { float4 t; t.x=acc[j][0]; t.y=acc[j][1]; t.z=acc[j][2]; t.w=acc[j][3];
                     *(float4*)(out + n * C + oc0) = t; }
    }
}

// ---------- launch ----------
extern "C" void kernel_launch(void* const* d_in, const int* in_sizes, int n_in,
                              void* d_out, int out_size, void* d_ws, size_t ws_size,
                              hipStream_t stream)
{
    const float* x     = (const float*)d_in[0];
    const float* pos   = (const float*)d_in[1];
    const int*   ei    = (const int*)  d_in[2];
    const float* W_in  = (const float*)d_in[3];
    const float* b_in  = (const float*)d_in[4];
    const float* W_lin = (const float*)d_in[5];
    const float* W_src = (const float*)d_in[6];
    const float* W_dst = (const float*)d_in[7];
    const float* pw1   = (const float*)d_in[8];
    const float* pb1   = (const float*)d_in[9];
    const float* pw2   = (const float*)d_in[10];
    const float* pb2   = (const float*)d_in[11];
    const float* aw1   = (const float*)d_in[12];
    const float* ab1   = (const float*)d_in[13];
    const float* aw2   = (const float*)d_in[14];
    const float* ab2   = (const float*)d_in[15];
    const float* W_out = (const float*)d_in[16];
    const float* b_out = (const float*)d_in[17];

    const int N = in_sizes[0] / C;
    const int E = in_sizes[2] / 2;

    float* z    = (float*)d_ws;                  // [N,C]
    float* aggU = z    + (size_t)N * C;          // [N,C]
    float* q    = aggU + (size_t)N * C;          // [N,C]
    float* k    = q    + (size_t)N * C;          // [N,C]
    float* v    = k    + (size_t)N * C;          // [N,C]

    // zero the accumulators (ws is poisoned 0xAA before every call)
    hipMemsetAsync(z, 0, (size_t)2 * N * C * sizeof(float), stream);

    const int nb = (N + TILE - 1) / TILE;
    const int eb = (E + TILE - 1) / TILE;

    node_qkv<<<nb, THREADS, 0, stream>>>(x, W_in, b_in, W_lin, W_src, W_dst, q, k, v, N);
    edge_kernel<<<eb, THREADS, 0, stream>>>(pos, ei, q, k, v,
                                            pw1, pb1, pw2, pb2,
                                            aw1, ab1, aw2, ab2, z, aggU, E);
    out_kernel<<<nb, THREADS, 0, stream>>>(aggU, z, W_out, b_out, (float*)d_out, N);
}

// Round 3
// 1043.746 us; speedup vs baseline: 3.1437x; 3.1330x over previous
//
#include <hip/hip_runtime.h>

#define C 128
#define THREADS 256
#define TILE 64          // node rows per block (fp32 kernels)
#define EPB 64           // edges per block (mfma kernel)
#define EPW 16           // edges per wave
#define LDSPAD 8
#define LDSW (C + LDSPAD)   // 136 ushorts/row: +16B pad -> 2-way-only LDS banks

typedef unsigned short ushortT;
typedef __attribute__((ext_vector_type(8))) short short8;
typedef __attribute__((ext_vector_type(8))) ushortT ushort8;
typedef __attribute__((ext_vector_type(4))) float floatx4;

// ---- bf16 helpers (RNE) ----
__device__ __forceinline__ ushortT f2bf(float x) {
    union { float f; unsigned u; } v; v.f = x;
    unsigned r = v.u + 0x7FFFu + ((v.u >> 16) & 1u);
    return (ushortT)(r >> 16);
}
__device__ __forceinline__ float bf2f(ushortT h) {
    union { unsigned u; float f; } v; v.u = ((unsigned)h) << 16;
    return v.f;
}
__device__ __forceinline__ void atomic_add_f32(float* p, float v) {
    __hip_atomic_fetch_add(p, v, __ATOMIC_RELAXED, __HIP_MEMORY_SCOPE_AGENT);
}

// ============================================================================
// fp32 micro-GEMM helpers for the (cheap) node-level kernels — unchanged math
// ============================================================================
__device__ __forceinline__ void zero_acc(float acc[8][4]) {
#pragma unroll
    for (int j = 0; j < 8; ++j)
#pragma unroll
        for (int i = 0; i < 4; ++i) acc[j][i] = 0.f;
}

__device__ __forceinline__ void tile_gemm(const float* __restrict__ s_in,
                                          const float* __restrict__ W,
                                          float acc[8][4], int rg, int oc0)
{
#pragma unroll 2
    for (int kc = 0; kc < C; kc += 4) {
        const float4 w0 = *(const float4*)(W + (kc + 0) * C + oc0);
        const float4 w1 = *(const float4*)(W + (kc + 1) * C + oc0);
        const float4 w2 = *(const float4*)(W + (kc + 2) * C + oc0);
        const float4 w3 = *(const float4*)(W + (kc + 3) * C + oc0);
#pragma unroll
        for (int j = 0; j < 8; ++j) {
            const float4 a = *(const float4*)(s_in + (rg * 8 + j) * C + kc);
            acc[j][0] = fmaf(a.w, w3.x, fmaf(a.z, w2.x, fmaf(a.y, w1.x, fmaf(a.x, w0.x, acc[j][0]))));
            acc[j][1] = fmaf(a.w, w3.y, fmaf(a.z, w2.y, fmaf(a.y, w1.y, fmaf(a.x, w0.y, acc[j][1]))));
            acc[j][2] = fmaf(a.w, w3.z, fmaf(a.z, w2.z, fmaf(a.y, w1.z, fmaf(a.x, w0.z, acc[j][2]))));
            acc[j][3] = fmaf(a.w, w3.w, fmaf(a.z, w2.w, fmaf(a.y, w1.w, fmaf(a.x, w0.w, acc[j][3]))));
        }
    }
}

__device__ __forceinline__ void bias_relu(float acc[8][4], const float* __restrict__ b, int oc0) {
    const float4 bv = *(const float4*)(b + oc0);
#pragma unroll
    for (int j = 0; j < 8; ++j) {
        acc[j][0] = fmaxf(acc[j][0] + bv.x, 0.f);
        acc[j][1] = fmaxf(acc[j][1] + bv.y, 0.f);
        acc[j][2] = fmaxf(acc[j][2] + bv.z, 0.f);
        acc[j][3] = fmaxf(acc[j][3] + bv.w, 0.f);
    }
}

__device__ __forceinline__ void store_tile(float* __restrict__ s, const float acc[8][4], int rg, int oc0) {
#pragma unroll
    for (int j = 0; j < 8; ++j) {
        float4 t; t.x = acc[j][0]; t.y = acc[j][1]; t.z = acc[j][2]; t.w = acc[j][3];
        *(float4*)(s + (rg * 8 + j) * C + oc0) = t;
    }
}

// ============================================================================
// kernel: pack 4 weight matrices into exact MFMA B-fragment order (bf16)
// B[k][n] fragment: lane L holds k = (L>>4)*8 + j, n = L&15, for tile
// (ntile, kstep); flat index = ((s*32 + nt*4+ks)*64 + lane)*8 + j  == tid.
// ============================================================================
extern "C" __global__ void pack_w(const float* __restrict__ w0, const float* __restrict__ w1,
                                  const float* __restrict__ w2, const float* __restrict__ w3,
                                  ushortT* __restrict__ out)
{
    const int t = blockIdx.x * 256 + threadIdx.x;      // 4*32*64*8 = 65536 threads
    const int j = t & 7, lane = (t >> 3) & 63, f = (t >> 9) & 31, s = t >> 14;
    const float* W = (s == 0) ? w0 : (s == 1) ? w1 : (s == 2) ? w2 : w3;
    const int n = (f >> 2) * 16 + (lane & 15);
    const int k = (f & 3) * 32 + (lane >> 4) * 8 + j;
    out[t] = f2bf(W[k * C + n]);
}

// fp32 -> bf16 table convert
extern "C" __global__ void cvt_bf(const float* __restrict__ in, ushortT* __restrict__ out, int n)
{
    const int t = blockIdx.x * 256 + threadIdx.x;
    if (t < n) out[t] = f2bf(in[t]);
}

// ============================================================================
// kernel 1: h = relu(x@W_in+b_in); q_bf = bf16(h@W_dst); k_bf = bf16(h@W_src);
//           v = h@W_lin (fp32)
// ============================================================================
extern "C" __global__ void __launch_bounds__(THREADS)
node_qkv(const float* __restrict__ x,
         const float* __restrict__ W_in, const float* __restrict__ b_in,
         const float* __restrict__ W_lin, const float* __restrict__ W_src, const float* __restrict__ W_dst,
         ushortT* __restrict__ q_bf, ushortT* __restrict__ k_bf, float* __restrict__ v, int N)
{
    __shared__ __align__(16) float s_in[TILE * C];
    const int tx = threadIdx.x;
    const int rg = tx >> 5;
    const int oc0 = (tx & 31) << 2;
    const int row0 = blockIdx.x * TILE;

#pragma unroll
    for (int j = 0; j < 8; ++j) {
        const int r = rg * 8 + j, n = row0 + r;
        float4 xv; xv.x = xv.y = xv.z = xv.w = 0.f;
        if (n < N) xv = *(const float4*)(x + n * C + oc0);
        *(float4*)(s_in + r * C + oc0) = xv;
    }

    float acc[8][4];
    zero_acc(acc);
    tile_gemm(s_in, W_in, acc, rg, oc0);
    bias_relu(acc, b_in, oc0);
    store_tile(s_in, acc, rg, oc0);          // s_in = h

    // q_bf = bf16(h @ W_dst)
    zero_acc(acc);
    tile_gemm(s_in, W_dst, acc, rg, oc0);
#pragma unroll
    for (int j = 0; j < 8; ++j) {
        const int n = row0 + rg * 8 + j;
        if (n < N) {
            ushort4 t; t.x = f2bf(acc[j][0]); t.y = f2bf(acc[j][1]);
            t.z = f2bf(acc[j][2]); t.w = f2bf(acc[j][3]);
            *(ushort4*)(q_bf + (size_t)n * C + oc0) = t;
        }
    }
    // k_bf = bf16(h @ W_src)
    zero_acc(acc);
    tile_gemm(s_in, W_src, acc, rg, oc0);
#pragma unroll
    for (int j = 0; j < 8; ++j) {
        const int n = row0 + rg * 8 + j;
        if (n < N) {
            ushort4 t; t.x = f2bf(acc[j][0]); t.y = f2bf(acc[j][1]);
            t.z = f2bf(acc[j][2]); t.w = f2bf(acc[j][3]);
            *(ushort4*)(k_bf + (size_t)n * C + oc0) = t;
        }
    }
    // v = h @ W_lin  (fp32, used in msg epilogue)
    zero_acc(acc);
    tile_gemm(s_in, W_lin, acc, rg, oc0);
#pragma unroll
    for (int j = 0; j < 8; ++j) {
        const int n = row0 + rg * 8 + j;
        if (n < N) { float4 t; t.x=acc[j][0]; t.y=acc[j][1]; t.z=acc[j][2]; t.w=acc[j][3];
                     *(float4*)(v + (size_t)n * C + oc0) = t; }
    }
}

// ============================================================================
// kernel 2 (MFMA): per-edge 2x 2-layer MLPs + softmax-numerator atomics.
// Block = 4 independent waves x 16 edges; per-wave private LDS slab; NO barriers.
// A-frag:  A[m=lane&15][k=quad*8+j]   (m120-verified layout)
// C-frag:  C[m=quad*4+reg][n=lane&15] (m89-verified layout)
// ============================================================================
__device__ __forceinline__ void wave_gemm(const ushortT (*A)[LDSW],
                                          const ushortT* __restrict__ Bp,
                                          int quad, int m16, int lane,
                                          floatx4 acc[8])
{
    short8 af[4];
#pragma unroll
    for (int ks = 0; ks < 4; ++ks)
        af[ks] = *(const short8*)&A[m16][ks * 32 + quad * 8];
#pragma unroll
    for (int nt = 0; nt < 8; ++nt) {
#pragma unroll
        for (int ks = 0; ks < 4; ++ks) {
            const short8 bf = *(const short8*)(Bp + ((size_t)((nt * 4 + ks) * 64 + lane)) * 8);
            acc[nt] = __builtin_amdgcn_mfma_f32_16x16x32_bf16(af[ks], bf, acc[nt], 0, 0, 0);
        }
    }
}

__device__ __forceinline__ void zero8(floatx4 acc[8]) {
#pragma unroll
    for (int nt = 0; nt < 8; ++nt) { acc[nt][0]=0.f; acc[nt][1]=0.f; acc[nt][2]=0.f; acc[nt][3]=0.f; }
}

// C-layout -> relu(x+bias) -> bf16 -> slab (A-layout for next stage)
__device__ __forceinline__ void cstore_relu(ushortT (*A)[LDSW], floatx4 acc[8],
                                            const float* __restrict__ bias, int quad, int m16)
{
#pragma unroll
    for (int nt = 0; nt < 8; ++nt) {
        const float b = bias[nt * 16 + m16];
#pragma unroll
        for (int r = 0; r < 4; ++r) {
            A[quad * 4 + r][nt * 16 + m16] = f2bf(fmaxf(acc[nt][r] + b, 0.f));
        }
    }
}

extern "C" __global__ void __launch_bounds__(THREADS)
edge_mfma(const ushortT* __restrict__ pos_bf, const int* __restrict__ ei,
          const ushortT* __restrict__ q_bf, const ushortT* __restrict__ k_bf,
          const float* __restrict__ v, const ushortT* __restrict__ Bpack,
          const float* __restrict__ pb1, const float* __restrict__ pb2,
          const float* __restrict__ ab1, const float* __restrict__ ab2,
          float* __restrict__ z, float* __restrict__ aggU, int E)
{
    __shared__ ushortT slab[4][EPW][LDSW];
    const int tid = threadIdx.x;
    const int wv = tid >> 6, lane = tid & 63;
    const int quad = lane >> 4, m16 = lane & 15;
    const int e_base = blockIdx.x * EPB + wv * EPW;
    ushortT (*A)[LDSW] = slab[wv];

    // coop-staging lane mapping: each lane owns (row, 32-col segment)
    const int row = lane >> 2, seg = lane & 3;
    const int eidx = min(e_base + row, E - 1);
    const int es = ei[eidx];          // src
    const int ed = ei[E + eidx];      // dst

    // ---- A0 = bf16(pos[dst] - pos[src]) ----
    {
        const ushort8* pd = (const ushort8*)(pos_bf + (size_t)ed * C + seg * 32);
        const ushort8* ps = (const ushort8*)(pos_bf + (size_t)es * C + seg * 32);
#pragma unroll
        for (int i = 0; i < 4; ++i) {
            ushort8 a = pd[i], b = ps[i], o;
#pragma unroll
            for (int t = 0; t < 8; ++t) o[t] = f2bf(bf2f(a[t]) - bf2f(b[t]));
            *(ushort8*)&A[row][seg * 32 + i * 8] = o;
        }
    }

    floatx4 acc[8];

    // ---- pos_nn layer 1 ----
    zero8(acc);
    wave_gemm(A, Bpack + 0 * 16384, quad, m16, lane, acc);
    cstore_relu(A, acc, pb1, quad, m16);

    // ---- pos_nn layer 2 -> delta (keep in regs, also -> slab) ----
    zero8(acc);
    wave_gemm(A, Bpack + 1 * 16384, quad, m16, lane, acc);
    float dl[8][4];
#pragma unroll
    for (int nt = 0; nt < 8; ++nt) {
        const float b = pb2[nt * 16 + m16];
#pragma unroll
        for (int r = 0; r < 4; ++r) dl[nt][r] = fmaxf(acc[nt][r] + b, 0.f);
    }
#pragma unroll
    for (int nt = 0; nt < 8; ++nt)
#pragma unroll
        for (int r = 0; r < 4; ++r)
            A[quad * 4 + r][nt * 16 + m16] = f2bf(dl[nt][r]);

    // ---- A2 = bf16( q[dst] - k[src] + delta ) ----
    {
        const ushort8* qp = (const ushort8*)(q_bf + (size_t)ed * C + seg * 32);
        const ushort8* kp = (const ushort8*)(k_bf + (size_t)es * C + seg * 32);
#pragma unroll
        for (int i = 0; i < 4; ++i) {
            ushort8 qv = qp[i], kv = kp[i];
            ushort8 dv = *(ushort8*)&A[row][seg * 32 + i * 8], o;
#pragma unroll
            for (int t = 0; t < 8; ++t)
                o[t] = f2bf(bf2f(qv[t]) - bf2f(kv[t]) + bf2f(dv[t]));
            *(ushort8*)&A[row][seg * 32 + i * 8] = o;
        }
    }

    // ---- attn_nn layer 1 ----
    zero8(acc);
    wave_gemm(A, Bpack + 2 * 16384, quad, m16, lane, acc);
    cstore_relu(A, acc, ab1, quad, m16);

    // ---- attn_nn layer 2 -> alpha -> ea = exp(relu(alpha)) in acc ----
    zero8(acc);
    wave_gemm(A, Bpack + 3 * 16384, quad, m16, lane, acc);
#pragma unroll
    for (int nt = 0; nt < 8; ++nt) {
        const float b = ab2[nt * 16 + m16];
#pragma unroll
        for (int r = 0; r < 4; ++r)
            acc[nt][r] = __expf(fmaxf(acc[nt][r] + b, 0.f));   // alpha>=0, O(1): no max-shift needed
    }

    // ---- epilogue: z[dst,c] += ea; aggU[dst,c] += ea*(v[src,c]+delta[c]) ----
    int ssr[4], sdr[4];
#pragma unroll
    for (int r = 0; r < 4; ++r) {
        const int e = min(e_base + quad * 4 + r, E - 1);
        ssr[r] = ei[e]; sdr[r] = ei[E + e];
    }
    const bool tail = (e_base + EPW > E);
#pragma unroll
    for (int nt = 0; nt < 8; ++nt) {
        const int c = nt * 16 + m16;
#pragma unroll
        for (int r = 0; r < 4; ++r) {
            if (tail && (e_base + quad * 4 + r >= E)) continue;
            const float ea = acc[nt][r];
            const float vv = v[(size_t)ssr[r] * C + c];
            atomic_add_f32(z    + (size_t)sdr[r] * C + c, ea);
            atomic_add_f32(aggU + (size_t)sdr[r] * C + c, ea * (vv + dl[nt][r]));
        }
    }
}

// ============================================================================
// kernel 3: out = relu( (aggU / (z+1e-16)) @ W_out + b_out )
// ============================================================================
extern "C" __global__ void __launch_bounds__(THREADS)
out_kernel(const float* __restrict__ aggU, const float* __restrict__ z,
           const float* __restrict__ W_out, const float* __restrict__ b_out,
           float* __restrict__ out, int N)
{
    __shared__ __align__(16) float s_in[TILE * C];
    const int tx = threadIdx.x;
    const int rg = tx >> 5;
    const int oc0 = (tx & 31) << 2;
    const int row0 = blockIdx.x * TILE;

#pragma unroll
    for (int j = 0; j < 8; ++j) {
        const int r = rg * 8 + j, n = row0 + r;
        float4 a; a.x = a.y = a.z = a.w = 0.f;
        if (n < N) {
            const float4 g  = *(const float4*)(aggU + (size_t)n * C + oc0);
            const float4 zz = *(const float4*)(z    + (size_t)n * C + oc0);
            a.x = g.x / (zz.x + 1e-16f);
            a.y = g.y / (zz.y + 1e-16f);
            a.z = g.z / (zz.z + 1e-16f);
            a.w = g.w / (zz.w + 1e-16f);
        }
        *(float4*)(s_in + r * C + oc0) = a;
    }

    float acc[8][4];
    zero_acc(acc);
    tile_gemm(s_in, W_out, acc, rg, oc0);
    bias_relu(acc, b_out, oc0);
#pragma unroll
    for (int j = 0; j < 8; ++j) {
        const int n = row0 + rg * 8 + j;
        if (n < N) { float4 t; t.x=acc[j][0]; t.y=acc[j][1]; t.z=acc[j][2]; t.w=acc[j][3];
                     *(float4*)(out + (size_t)n * C + oc0) = t; }
    }
}

// ---------------------------------------------------------------------------
extern "C" void kernel_launch(void* const* d_in, const int* in_sizes, int n_in,
                              void* d_out, int out_size, void* d_ws, size_t ws_size,
                              hipStream_t stream)
{
    const float* x     = (const float*)d_in[0];
    const float* pos   = (const float*)d_in[1];
    const int*   ei    = (const int*)  d_in[2];
    const float* W_in  = (const float*)d_in[3];
    const float* b_in  = (const float*)d_in[4];
    const float* W_lin = (const float*)d_in[5];
    const float* W_src = (const float*)d_in[6];
    const float* W_dst = (const float*)d_in[7];
    const float* pw1   = (const float*)d_in[8];
    const float* pb1   = (const float*)d_in[9];
    const float* pw2   = (const float*)d_in[10];
    const float* pb2   = (const float*)d_in[11];
    const float* aw1   = (const float*)d_in[12];
    const float* ab1   = (const float*)d_in[13];
    const float* aw2   = (const float*)d_in[14];
    const float* ab2   = (const float*)d_in[15];
    const float* W_out = (const float*)d_in[16];
    const float* b_out = (const float*)d_in[17];

    const int N = in_sizes[0] / C;
    const int E = in_sizes[2] / 2;

    // workspace layout
    float*   z      = (float*)d_ws;                          // [N,C] fp32
    float*   aggU   = z    + (size_t)N * C;                  // [N,C] fp32
    float*   v      = aggU + (size_t)N * C;                  // [N,C] fp32
    ushortT* q_bf   = (ushortT*)(v + (size_t)N * C);         // [N,C] bf16
    ushortT* k_bf   = q_bf + (size_t)N * C;                  // [N,C] bf16
    ushortT* pos_bf = k_bf + (size_t)N * C;                  // [N,C] bf16
    ushortT* Bpack  = pos_bf + (size_t)N * C;                // 4*32*64*8 bf16 = 128KB

    hipMemsetAsync(z, 0, (size_t)2 * N * C * sizeof(float), stream);

    pack_w<<<256, 256, 0, stream>>>(pw1, pw2, aw1, aw2, Bpack);
    cvt_bf<<<(N * C + 255) / 256, 256, 0, stream>>>(pos, pos_bf, N * C);

    const int nb = (N + TILE - 1) / TILE;
    const int eb = (E + EPB - 1) / EPB;

    node_qkv<<<nb, THREADS, 0, stream>>>(x, W_in, b_in, W_lin, W_src, W_dst, q_bf, k_bf, v, N);
    edge_mfma<<<eb, THREADS, 0, stream>>>(pos_bf, ei, q_bf, k_bf, v, Bpack,
                                          pb1, pb2, ab1, ab2, z, aggU, E);
    out_kernel<<<nb, THREADS, 0, stream>>>(aggU, z, W_out, b_out, (float*)d_out, N);
}